// Round 3
// baseline (3121.442 us; speedup 1.0000x reference)
//
#include <hip/hip_runtime.h>
#include <math.h>

// N=50000 nodes, E=800000 edges, C=64, R=8, H=64, S=10
// Output row layout (512 floats/node): [mi0:64 | mi1:192 | res0:64 | res1:192]
// h0/h1 (linear_up output) live temporarily in cols 256:512 of d_out; the
// edge phase accumulates T0/T1 into cols 0:256; finalize reads both regions
// then overwrites 256:512 with res.
//
// FAST PATH: CSR (dst-sorted edge ids) built per call, then a node-owned
// gather kernel. This round: ONE 1024-thread block per CU owning NB=64
// nodes (~1024 edges), full W2 in LDS (loaded once per block, 52 MB total
// reload vs 283 MB sliced). LDS = 2K W1 + 64K W2 + 64*257*4 acc = 130.2 KB
// -> 1 block/CU but 16 resident waves, ~all with work. __launch_bounds__(1024)
// caps VGPR at 128 (round-1 inner loop compiled to exactly 128).

#define NB 64        // nodes per gather block
#define ACCS 257     // acc row stride (pad: neighbor-dst lanes land on distinct banks)

__device__ __forceinline__ float silu(float x) {
    return x / (1.0f + __expf(-x));
}

// ---------------- linear_up: h0 = nf0@Wup0, h1[n,o,i] = sum_c nf1[n,c,i]*Wup1[c,o]
__global__ __launch_bounds__(256) void up_kernel(
    const float* __restrict__ nf0, const float* __restrict__ nf1,
    const float* __restrict__ Wup0, const float* __restrict__ Wup1,
    float* __restrict__ out, int Nn) {
    __shared__ float sW0[4096];
    __shared__ float sW1u[4096];
    __shared__ float s0[4 * 64];
    __shared__ float s1[4 * 192];
    int t = threadIdx.x;
    for (int i = t; i < 4096; i += 256) { sW0[i] = Wup0[i]; sW1u[i] = Wup1[i]; }
    int n0 = blockIdx.x * 4;
    {
        int n = n0 + (t >> 6);
        s0[t] = (n < Nn) ? nf0[(size_t)n * 64 + (t & 63)] : 0.f;
    }
    for (int i = t; i < 768; i += 256) {
        int n = n0 + i / 192;
        s1[i] = (n < Nn) ? nf1[(size_t)n * 192 + (i % 192)] : 0.f;
    }
    __syncthreads();
    int w = t >> 6, o = t & 63;
    int n = n0 + w;
    if (n >= Nn) return;
    float a0 = 0.f, ax = 0.f, ay = 0.f, az = 0.f;
#pragma unroll 8
    for (int c = 0; c < 64; c++) {
        float w0 = sW0[c * 64 + o];
        float w1 = sW1u[c * 64 + o];
        float f0 = s0[w * 64 + c];
        a0 += f0 * w0;
        ax += s1[w * 192 + c * 3 + 0] * w1;
        ay += s1[w * 192 + c * 3 + 1] * w1;
        az += s1[w * 192 + c * 3 + 2] * w1;
    }
    float* row = out + (size_t)n * 512;
    row[256 + o] = a0;
    row[320 + o * 3 + 0] = ax;
    row[320 + o * 3 + 1] = ay;
    row[320 + o * 3 + 2] = az;
}

// ---------------- CSR build: histogram, exclusive scan, fill
__global__ __launch_bounds__(256) void hist_kernel(
    const int* __restrict__ ei, int* __restrict__ cnt, int E) {
    int e = blockIdx.x * 256 + threadIdx.x;
    if (e < E) atomicAdd(&cnt[ei[(size_t)E + e]], 1);
}

__global__ __launch_bounds__(1024) void scan_kernel(
    int* __restrict__ cnt, int* __restrict__ cur, int Nn, int E) {
    __shared__ int wsum[16];
    __shared__ int carry_s;
    int t = threadIdx.x;
    int lane = t & 63, wid = t >> 6;
    if (t == 0) carry_s = 0;
    __syncthreads();
    int nchunk = (Nn + 1023) >> 10;
    for (int ch = 0; ch < nchunk; ch++) {
        int i = (ch << 10) + t;
        int v = (i < Nn) ? cnt[i] : 0;
        int s = v;
#pragma unroll
        for (int d = 1; d < 64; d <<= 1) {
            int u = __shfl_up(s, d);
            if (lane >= d) s += u;
        }
        if (lane == 63) wsum[wid] = s;
        __syncthreads();
        int carry = carry_s;
        if (wid == 0) {
            int x = (lane < 16) ? wsum[lane] : 0;
#pragma unroll
            for (int d = 1; d < 16; d <<= 1) {
                int u = __shfl_up(x, d);
                if (lane >= d) x += u;
            }
            if (lane < 16) wsum[lane] = x;
        }
        __syncthreads();
        int woff = wid ? wsum[wid - 1] : 0;
        int excl = carry + woff + (s - v);
        if (i < Nn) { cnt[i] = excl; cur[i] = excl; }
        __syncthreads();
        if (t == 1023) carry_s = carry + wsum[15];
        __syncthreads();
    }
    if (t == 0) cnt[Nn] = E;
}

__global__ __launch_bounds__(256) void fill_kernel(
    const int* __restrict__ ei, int* __restrict__ cur, int* __restrict__ csr, int E) {
    int e = blockIdx.x * 256 + threadIdx.x;
    if (e < E) {
        int pos = atomicAdd(&cur[ei[(size_t)E + e]], 1);
        csr[pos] = e;
    }
}

// ---------------- node-owned gather: 1024 threads, NB=64 nodes, full W2
__global__ __launch_bounds__(1024) void gather_kernel(
    const float* __restrict__ edge_feats, const float* __restrict__ edge_attrs1,
    const float* __restrict__ cutoff, const int* __restrict__ ei,
    const int* __restrict__ offs, const int* __restrict__ csr,
    const float* __restrict__ W1g, const float* __restrict__ W2g,
    float* __restrict__ out, int Nn, int E) {
    __shared__ __align__(16) float sW1[8 * 64];        // 2 KB
    __shared__ __align__(16) float sW2[64 * 256];      // 64 KB
    __shared__ float acc[NB * ACCS];                   // 64.25 KB -> 130.2 KB total
    int t = threadIdx.x;
    if (t < 512) sW1[t] = W1g[t];
    {
        float4* d4 = reinterpret_cast<float4*>(sW2);
        const float4* s4 = reinterpret_cast<const float4*>(W2g);
        for (int i = t; i < 4096; i += 1024) d4[i] = s4[i];
    }
    for (int i = t; i < NB * ACCS; i += 1024) acc[i] = 0.f;
    int n0 = blockIdx.x * NB;
    int nend = n0 + NB; if (nend > Nn) nend = Nn;
    int pbeg = offs[n0];
    int pend = offs[nend];
    __syncthreads();

    const float4* w2v = reinterpret_cast<const float4*>(sW2);
#pragma unroll 1
    for (int p = pbeg + t; p < pend; p += 1024) {
        int e = csr[p];
        int src = ei[e];
        int dst = ei[(size_t)E + e];

        float ef[8];
        {
            const float4* pe = reinterpret_cast<const float4*>(edge_feats + (size_t)e * 8);
            float4 a = pe[0], b = pe[1];
            ef[0] = a.x; ef[1] = a.y; ef[2] = a.z; ef[3] = a.w;
            ef[4] = b.x; ef[5] = b.y; ef[6] = b.z; ef[7] = b.w;
        }
        // hidden = silu(ef @ W1)  -- wave-uniform LDS broadcast reads
        float h[64];
#pragma unroll
        for (int hg = 0; hg < 16; hg++) {
            float ax = 0.f, ay = 0.f, az = 0.f, aw = 0.f;
#pragma unroll
            for (int rr = 0; rr < 8; rr++) {
                const float4 wv = *reinterpret_cast<const float4*>(&sW1[rr * 64 + hg * 4]);
                ax += ef[rr] * wv.x; ay += ef[rr] * wv.y;
                az += ef[rr] * wv.z; aw += ef[rr] * wv.w;
            }
            h[hg * 4 + 0] = silu(ax);
            h[hg * 4 + 1] = silu(ay);
            h[hg * 4 + 2] = silu(az);
            h[hg * 4 + 3] = silu(aw);
        }

        float cut = cutoff[e];
        float sh0 = edge_attrs1[(size_t)e * 3 + 0];
        float sh1v = edge_attrs1[(size_t)e * 3 + 1];
        float sh2 = edge_attrs1[(size_t)e * 3 + 2];
        const float* h0r = out + (size_t)src * 512 + 256;
        const float* h1r = out + (size_t)src * 512 + 320;
        float* ab = acc + (dst - n0) * ACCS;

#pragma unroll 1
        for (int cg = 0; cg < 16; cg++) {
            int c0 = cg * 4;
            // gather loads issued FIRST: L3 latency hides under the l-loop
            float4 h0v = *reinterpret_cast<const float4*>(h0r + c0);
            float4 q0 = *reinterpret_cast<const float4*>(h1r + c0 * 3);
            float4 q1 = *reinterpret_cast<const float4*>(h1r + c0 * 3 + 4);
            float4 q2 = *reinterpret_cast<const float4*>(h1r + c0 * 3 + 8);

            float a00[4] = {0.f, 0.f, 0.f, 0.f};
            float a11[4] = {0.f, 0.f, 0.f, 0.f};
            float a01[4] = {0.f, 0.f, 0.f, 0.f};
            float a10[4] = {0.f, 0.f, 0.f, 0.f};
#pragma unroll
            for (int l = 0; l < 64; l++) {
                float hl = h[l];
                float4 w00v = w2v[l * 64 + cg];        // wave-uniform b128 broadcast
                float4 w11v = w2v[l * 64 + 16 + cg];
                float4 w01v = w2v[l * 64 + 32 + cg];
                float4 w10v = w2v[l * 64 + 48 + cg];
                a00[0] += hl * w00v.x; a00[1] += hl * w00v.y; a00[2] += hl * w00v.z; a00[3] += hl * w00v.w;
                a11[0] += hl * w11v.x; a11[1] += hl * w11v.y; a11[2] += hl * w11v.z; a11[3] += hl * w11v.w;
                a01[0] += hl * w01v.x; a01[1] += hl * w01v.y; a01[2] += hl * w01v.z; a01[3] += hl * w01v.w;
                a10[0] += hl * w10v.x; a10[1] += hl * w10v.y; a10[2] += hl * w10v.z; a10[3] += hl * w10v.w;
            }
            float h0a[4] = {h0v.x, h0v.y, h0v.z, h0v.w};
            float h1a[12] = {q0.x, q0.y, q0.z, q0.w, q1.x, q1.y, q1.z, q1.w,
                             q2.x, q2.y, q2.z, q2.w};
#pragma unroll
            for (int k = 0; k < 4; k++) {
                int c = c0 + k;
                float he0 = h0a[k];
                float e0 = h1a[k * 3 + 0], e1 = h1a[k * 3 + 1], e2 = h1a[k * 3 + 2];
                float d = e0 * sh0 + e1 * sh1v + e2 * sh2;
                float m0 = (a00[k] * he0 + a11[k] * d) * cut;
                atomicAdd(ab + c, m0);                      // ds_add_f32 (LDS)
                float wa = a01[k] * he0 * cut;
                float wb = a10[k] * cut;
                atomicAdd(ab + 64 + c * 3 + 0, wa * sh0 + wb * e0);
                atomicAdd(ab + 64 + c * 3 + 1, wa * sh1v + wb * e1);
                atomicAdd(ab + 64 + c * 3 + 2, wa * sh2 + wb * e2);
            }
        }
    }
    __syncthreads();
    // plain coalesced store of raw T0/T1 (finalize applies 1/16 and Q)
    int nb = nend - n0;
    for (int i = t; i < nb * 256; i += 1024) {
        int ln = i >> 8, idx = i & 255;
        out[(size_t)(n0 + ln) * 512 + idx] = acc[ln * ACCS + idx];
    }
}

// ---------------- FALLBACK: original fused atomic-scatter edge kernel
__global__ __launch_bounds__(256, 2) void edge_kernel(
    const float* __restrict__ edge_feats, const float* __restrict__ edge_attrs1,
    const float* __restrict__ cutoff, const int* __restrict__ edge_index,
    const float* __restrict__ W1g, const float* __restrict__ W2g,
    float* __restrict__ out, int E) {
    __shared__ __align__(16) float sW1[8 * 64];
    __shared__ __align__(16) float sW2[64 * 256];
    int t = threadIdx.x;
    sW1[t] = W1g[t];
    sW1[t + 256] = W1g[t + 256];
    for (int i = t; i < 16384; i += 256) sW2[i] = W2g[i];
    __syncthreads();

    int e = blockIdx.x * 256 + t;
    if (e >= E) return;

    float ef[8];
    {
        const float4* p = reinterpret_cast<const float4*>(edge_feats + (size_t)e * 8);
        float4 a = p[0], b = p[1];
        ef[0] = a.x; ef[1] = a.y; ef[2] = a.z; ef[3] = a.w;
        ef[4] = b.x; ef[5] = b.y; ef[6] = b.z; ef[7] = b.w;
    }
    float h[64];
#pragma unroll
    for (int hg = 0; hg < 16; hg++) {
        float ax = 0.f, ay = 0.f, az = 0.f, aw = 0.f;
#pragma unroll
        for (int rr = 0; rr < 8; rr++) {
            const float4 wv = *reinterpret_cast<const float4*>(&sW1[rr * 64 + hg * 4]);
            ax += ef[rr] * wv.x; ay += ef[rr] * wv.y;
            az += ef[rr] * wv.z; aw += ef[rr] * wv.w;
        }
        h[hg * 4 + 0] = silu(ax);
        h[hg * 4 + 1] = silu(ay);
        h[hg * 4 + 2] = silu(az);
        h[hg * 4 + 3] = silu(aw);
    }

    int src = edge_index[e];
    int dst = edge_index[(size_t)E + e];
    float cut = cutoff[e];
    float sh0 = edge_attrs1[(size_t)e * 3 + 0];
    float sh1v = edge_attrs1[(size_t)e * 3 + 1];
    float sh2 = edge_attrs1[(size_t)e * 3 + 2];
    const float* h0r = out + (size_t)src * 512 + 256;
    const float* h1r = out + (size_t)src * 512 + 320;
    float* outr = out + (size_t)dst * 512;
    const float4* w2v = reinterpret_cast<const float4*>(sW2);

#pragma unroll 1
    for (int cg = 0; cg < 16; cg++) {
        float a00[4] = {0.f, 0.f, 0.f, 0.f};
        float a11[4] = {0.f, 0.f, 0.f, 0.f};
        float a01[4] = {0.f, 0.f, 0.f, 0.f};
        float a10[4] = {0.f, 0.f, 0.f, 0.f};
#pragma unroll
        for (int l = 0; l < 64; l++) {
            float hl = h[l];
            float4 w00v = w2v[l * 64 + cg];
            float4 w11v = w2v[l * 64 + 16 + cg];
            float4 w01v = w2v[l * 64 + 32 + cg];
            float4 w10v = w2v[l * 64 + 48 + cg];
            a00[0] += hl * w00v.x; a00[1] += hl * w00v.y; a00[2] += hl * w00v.z; a00[3] += hl * w00v.w;
            a11[0] += hl * w11v.x; a11[1] += hl * w11v.y; a11[2] += hl * w11v.z; a11[3] += hl * w11v.w;
            a01[0] += hl * w01v.x; a01[1] += hl * w01v.y; a01[2] += hl * w01v.z; a01[3] += hl * w01v.w;
            a10[0] += hl * w10v.x; a10[1] += hl * w10v.y; a10[2] += hl * w10v.z; a10[3] += hl * w10v.w;
        }
        int c0 = cg * 4;
        float4 h0v = *reinterpret_cast<const float4*>(h0r + c0);
        float4 q0 = *reinterpret_cast<const float4*>(h1r + c0 * 3);
        float4 q1 = *reinterpret_cast<const float4*>(h1r + c0 * 3 + 4);
        float4 q2 = *reinterpret_cast<const float4*>(h1r + c0 * 3 + 8);
        float h0a[4] = {h0v.x, h0v.y, h0v.z, h0v.w};
        float h1a[12] = {q0.x, q0.y, q0.z, q0.w, q1.x, q1.y, q1.z, q1.w,
                         q2.x, q2.y, q2.z, q2.w};
#pragma unroll
        for (int k = 0; k < 4; k++) {
            int c = c0 + k;
            float he0 = h0a[k];
            float e0 = h1a[k * 3 + 0], e1 = h1a[k * 3 + 1], e2 = h1a[k * 3 + 2];
            float d = e0 * sh0 + e1 * sh1v + e2 * sh2;
            float m0 = (a00[k] * he0 + a11[k] * d) * cut;
            atomicAdd(outr + c, m0);
            float wa = a01[k] * he0 * cut;
            float wb = a10[k] * cut;
            atomicAdd(outr + 64 + c * 3 + 0, wa * sh0 + wb * e0);
            atomicAdd(outr + 64 + c * 3 + 1, wa * sh1v + wb * e1);
            atomicAdd(outr + 64 + c * 3 + 2, wa * sh2 + wb * e2);
        }
    }
}

// ---------------- finalize: scale by 1/16, apply Q0/Q1, species residual
__global__ __launch_bounds__(256) void finalize_kernel(
    const float* __restrict__ node_attrs, const float* __restrict__ Wsc0,
    const float* __restrict__ Wsc1, const float* __restrict__ Q0,
    const float* __restrict__ Q1, float* __restrict__ out, int Nn) {
    __shared__ float smi0[4][64];
    __shared__ float smi1[4][192];
    int t = threadIdx.x;
    int w = t >> 6, o = t & 63;
    int n = blockIdx.x * 4 + w;
    const float inv = 1.0f / 16.0f;
    float q00 = Q0[0];
    float Q[9];
#pragma unroll
    for (int i = 0; i < 9; i++) Q[i] = Q1[i];
    if (n < Nn) {
        float* row = out + (size_t)n * 512;
        float t0 = row[o];
        float ta = row[64 + o * 3 + 0];
        float tb = row[64 + o * 3 + 1];
        float tc = row[64 + o * 3 + 2];
        float mi0 = t0 * inv * q00;
        float m0i = inv * (ta * Q[0] + tb * Q[3] + tc * Q[6]);
        float m1i = inv * (ta * Q[1] + tb * Q[4] + tc * Q[7]);
        float m2i = inv * (ta * Q[2] + tb * Q[5] + tc * Q[8]);
        row[o] = mi0;
        row[64 + o * 3 + 0] = m0i;
        row[64 + o * 3 + 1] = m1i;
        row[64 + o * 3 + 2] = m2i;
        smi0[w][o] = mi0;
        smi1[w][o * 3 + 0] = m0i;
        smi1[w][o * 3 + 1] = m1i;
        smi1[w][o * 3 + 2] = m2i;
    }
    __syncthreads();
    if (n >= Nn) return;
    float acc0 = 0.f, acc1x = 0.f, acc1y = 0.f, acc1z = 0.f;
    for (int s = 0; s < 10; s++) {
        float a = node_attrs[(size_t)n * 10 + s];
        if (a != 0.f) {
            const float* w0 = Wsc0 + s * 4096;
            const float* w1 = Wsc1 + s * 4096;
            float p0 = 0.f, px = 0.f, py = 0.f, pz = 0.f;
#pragma unroll 8
            for (int c = 0; c < 64; c++) {
                float v0 = w0[c * 64 + o];
                float v1 = w1[c * 64 + o];
                p0 += smi0[w][c] * v0;
                px += smi1[w][c * 3 + 0] * v1;
                py += smi1[w][c * 3 + 1] * v1;
                pz += smi1[w][c * 3 + 2] * v1;
            }
            acc0 += a * p0; acc1x += a * px; acc1y += a * py; acc1z += a * pz;
        }
    }
    float* row = out + (size_t)n * 512;
    row[256 + o] = acc0;
    row[320 + o * 3 + 0] = acc1x;
    row[320 + o * 3 + 1] = acc1y;
    row[320 + o * 3 + 2] = acc1z;
}

extern "C" void kernel_launch(void* const* d_in, const int* in_sizes, int n_in,
                              void* d_out, int out_size, void* d_ws, size_t ws_size,
                              hipStream_t stream) {
    const float* nf0   = (const float*)d_in[0];
    const float* nf1   = (const float*)d_in[1];
    const float* attrs = (const float*)d_in[2];
    const float* ef    = (const float*)d_in[3];
    const float* ea1   = (const float*)d_in[4];
    const float* cut   = (const float*)d_in[5];
    const float* Wup0  = (const float*)d_in[6];
    const float* Wup1  = (const float*)d_in[7];
    const float* W1    = (const float*)d_in[8];
    const float* W2    = (const float*)d_in[9];
    const float* Wsc0  = (const float*)d_in[10];
    const float* Wsc1  = (const float*)d_in[11];
    const float* Q0    = (const float*)d_in[12];
    const float* Q1    = (const float*)d_in[13];
    const int*   ei    = (const int*)d_in[14];
    int Nn = in_sizes[0] / 64;      // 50000
    int E  = in_sizes[14] / 2;      // 800000
    float* out = (float*)d_out;

    // ws layout (ints): cnt/offs [Nn+1] | cur [Nn] | csr [E]
    size_t need_bytes = ((size_t)(2 * Nn + 1) + (size_t)E) * sizeof(int);
    int ebl = (E + 255) / 256;

    if (d_ws != nullptr && ws_size >= need_bytes) {
        int* cnt = (int*)d_ws;
        int* cur = cnt + (Nn + 1);
        int* csr = cur + Nn;
        hipMemsetAsync(cnt, 0, (size_t)(Nn + 1) * sizeof(int), stream);
        hist_kernel<<<ebl, 256, 0, stream>>>(ei, cnt, E);
        scan_kernel<<<1, 1024, 0, stream>>>(cnt, cur, Nn, E);
        fill_kernel<<<ebl, 256, 0, stream>>>(ei, cur, csr, E);
        up_kernel<<<(Nn + 3) / 4, 256, 0, stream>>>(nf0, nf1, Wup0, Wup1, out, Nn);
        gather_kernel<<<(Nn + NB - 1) / NB, 1024, 0, stream>>>(
            ef, ea1, cut, ei, cnt, csr, W1, W2, out, Nn, E);
        finalize_kernel<<<(Nn + 3) / 4, 256, 0, stream>>>(attrs, Wsc0, Wsc1, Q0, Q1, out, Nn);
    } else {
        // fallback: original atomic-scatter path (out must be zeroed)
        hipMemsetAsync(out, 0, (size_t)out_size * sizeof(float), stream);
        up_kernel<<<(Nn + 3) / 4, 256, 0, stream>>>(nf0, nf1, Wup0, Wup1, out, Nn);
        edge_kernel<<<ebl, 256, 0, stream>>>(ef, ea1, cut, ei, W1, W2, out, E);
        finalize_kernel<<<(Nn + 3) / 4, 256, 0, stream>>>(attrs, Wsc0, Wsc1, Q0, Q1, out, Nn);
    }
}

// Round 4
// 1825.338 us; speedup vs baseline: 1.7101x; 1.7101x over previous
//
#include <hip/hip_runtime.h>
#include <math.h>

// N=50000 nodes, E=800000 edges, C=64, R=8, H=64, S=10
// Output row layout (512 floats/node): [mi0:64 | mi1:192 | res0:64 | res1:192]
// h0/h1 (linear_up output) live temporarily in cols 256:512 of d_out.
//
// FAST PATH: CSR (dst-sorted edge ids) built per call, then a node-owned
// 3-stage tile-pipelined gather kernel (256 thr, NB=16 nodes, 32-edge tiles):
//   stage0: gather h0/h1 rows + radial-MLP hidden into LDS tiles
//   stage1: register-blocked GEMM w = h @ W2 (4 edges x 8 ch per thread)
//   stage2: channel-parallel TP; wave j owns component j (T0,T1x,T1y,T1z),
//           lane = channel, register run-accumulation, ds_add only at
//           dst-change. Cuts LDS instrs/edge ~320 -> ~60 (the R1-R3 wall).

#define NB 16        // nodes per gather block
#define TE 32        // edges per tile

__device__ __forceinline__ float silu(float x) {
    return x / (1.0f + __expf(-x));
}

// ---------------- linear_up: h0 = nf0@Wup0, h1[n,o,i] = sum_c nf1[n,c,i]*Wup1[c,o]
__global__ __launch_bounds__(256) void up_kernel(
    const float* __restrict__ nf0, const float* __restrict__ nf1,
    const float* __restrict__ Wup0, const float* __restrict__ Wup1,
    float* __restrict__ out, int Nn) {
    __shared__ float sW0[4096];
    __shared__ float sW1u[4096];
    __shared__ float s0[4 * 64];
    __shared__ float s1[4 * 192];
    int t = threadIdx.x;
    for (int i = t; i < 4096; i += 256) { sW0[i] = Wup0[i]; sW1u[i] = Wup1[i]; }
    int n0 = blockIdx.x * 4;
    {
        int n = n0 + (t >> 6);
        s0[t] = (n < Nn) ? nf0[(size_t)n * 64 + (t & 63)] : 0.f;
    }
    for (int i = t; i < 768; i += 256) {
        int n = n0 + i / 192;
        s1[i] = (n < Nn) ? nf1[(size_t)n * 192 + (i % 192)] : 0.f;
    }
    __syncthreads();
    int w = t >> 6, o = t & 63;
    int n = n0 + w;
    if (n >= Nn) return;
    float a0 = 0.f, ax = 0.f, ay = 0.f, az = 0.f;
#pragma unroll 8
    for (int c = 0; c < 64; c++) {
        float w0 = sW0[c * 64 + o];
        float w1 = sW1u[c * 64 + o];
        float f0 = s0[w * 64 + c];
        a0 += f0 * w0;
        ax += s1[w * 192 + c * 3 + 0] * w1;
        ay += s1[w * 192 + c * 3 + 1] * w1;
        az += s1[w * 192 + c * 3 + 2] * w1;
    }
    float* row = out + (size_t)n * 512;
    row[256 + o] = a0;
    row[320 + o * 3 + 0] = ax;
    row[320 + o * 3 + 1] = ay;
    row[320 + o * 3 + 2] = az;
}

// ---------------- CSR build: histogram, exclusive scan, fill
__global__ __launch_bounds__(256) void hist_kernel(
    const int* __restrict__ ei, int* __restrict__ cnt, int E) {
    int e = blockIdx.x * 256 + threadIdx.x;
    if (e < E) atomicAdd(&cnt[ei[(size_t)E + e]], 1);
}

__global__ __launch_bounds__(1024) void scan_kernel(
    int* __restrict__ cnt, int* __restrict__ cur, int Nn, int E) {
    __shared__ int wsum[16];
    __shared__ int carry_s;
    int t = threadIdx.x;
    int lane = t & 63, wid = t >> 6;
    if (t == 0) carry_s = 0;
    __syncthreads();
    int nchunk = (Nn + 1023) >> 10;
    for (int ch = 0; ch < nchunk; ch++) {
        int i = (ch << 10) + t;
        int v = (i < Nn) ? cnt[i] : 0;
        int s = v;
#pragma unroll
        for (int d = 1; d < 64; d <<= 1) {
            int u = __shfl_up(s, d);
            if (lane >= d) s += u;
        }
        if (lane == 63) wsum[wid] = s;
        __syncthreads();
        int carry = carry_s;
        if (wid == 0) {
            int x = (lane < 16) ? wsum[lane] : 0;
#pragma unroll
            for (int d = 1; d < 16; d <<= 1) {
                int u = __shfl_up(x, d);
                if (lane >= d) x += u;
            }
            if (lane < 16) wsum[lane] = x;
        }
        __syncthreads();
        int woff = wid ? wsum[wid - 1] : 0;
        int excl = carry + woff + (s - v);
        if (i < Nn) { cnt[i] = excl; cur[i] = excl; }
        __syncthreads();
        if (t == 1023) carry_s = carry + wsum[15];
        __syncthreads();
    }
    if (t == 0) cnt[Nn] = E;
}

__global__ __launch_bounds__(256) void fill_kernel(
    const int* __restrict__ ei, int* __restrict__ cur, int* __restrict__ csr, int E) {
    int e = blockIdx.x * 256 + threadIdx.x;
    if (e < E) {
        int pos = atomicAdd(&cur[ei[(size_t)E + e]], 1);
        csr[pos] = e;
    }
}

#define FMA4(A, S, B) { (A).x += (S)*(B).x; (A).y += (S)*(B).y; (A).z += (S)*(B).z; (A).w += (S)*(B).w; }

// ---------------- 3-stage tile-pipelined node-owned gather
__global__ __launch_bounds__(256, 1) void gather_kernel(
    const float* __restrict__ edge_feats, const float* __restrict__ edge_attrs1,
    const float* __restrict__ cutoff, const int* __restrict__ ei,
    const int* __restrict__ offs, const int* __restrict__ csr,
    const float* __restrict__ W1g, const float* __restrict__ W2g,
    float* __restrict__ out, int Nn, int E) {
    __shared__ __align__(16) float sW1[512];          //  2048 B
    __shared__ __align__(16) float sW2[64 * 256];     // 65536 B
    __shared__ __align__(16) float h_t[TE * 68];      //  8704 B (hidden, pad 68)
    __shared__ __align__(16) float h0_t[TE * 68];     //  8704 B
    __shared__ __align__(16) float h1_t[TE * 196];    // 25088 B (pad 196)
    __shared__ __align__(16) float w_t[TE * 260];     // 33280 B (pad 260)
    __shared__ __align__(16) float accs[NB * 256];    // 16384 B
    __shared__ __align__(16) float4 meta4[TE];        //   512 B (sh0,sh1,sh2,cut)
    __shared__ int dstl[TE];                          //   128 B  => 160384 B total
    int t = threadIdx.x;

    for (int i = t; i < 512; i += 256) sW1[i] = W1g[i];
    {
        float4* d4 = reinterpret_cast<float4*>(sW2);
        const float4* s4 = reinterpret_cast<const float4*>(W2g);
        for (int i = t; i < 4096; i += 256) d4[i] = s4[i];
    }
    for (int i = t; i < NB * 256; i += 256) accs[i] = 0.f;
    int n0 = blockIdx.x * NB;
    int nend = n0 + NB; if (nend > Nn) nend = Nn;
    int pbeg = offs[n0];
    int pend = offs[nend];
    __syncthreads();

    // stage role indices
    int e0 = t >> 3, q = t & 7;          // stage 0: 32 edges x 8 slices
    int g = t >> 5, cs = t & 31;         // stage 1: 8 groups(4e) x 32 ch-slices
    int wv = t >> 6, c = t & 63;         // stage 2: wave=component, lane=channel
    int off2 = (wv == 0) ? c : (64 + c * 3 + (wv - 1));

    const float4* h4  = reinterpret_cast<const float4*>(h_t);   // row stride 17
    const float4* w24 = reinterpret_cast<const float4*>(sW2);   // row stride 64
    float4* wt4 = reinterpret_cast<float4*>(w_t);               // row stride 65

    float racc = 0.f;        // stage-2 run accumulator (persists across tiles)
    int prev = -1;

    for (int tb = pbeg; tb < pend; tb += TE) {
        int n_t = pend - tb; if (n_t > TE) n_t = TE;

        // ---- stage 0: gather + radial MLP hidden ----
        if (e0 < n_t) {
            int eg = csr[tb + e0];
            int src = ei[eg];
            if (q == 0) {
                dstl[e0] = ei[(size_t)E + eg] - n0;
                meta4[e0] = make_float4(edge_attrs1[(size_t)eg * 3 + 0],
                                        edge_attrs1[(size_t)eg * 3 + 1],
                                        edge_attrs1[(size_t)eg * 3 + 2],
                                        cutoff[eg]);
            }
            const float4* h0g = reinterpret_cast<const float4*>(out + (size_t)src * 512 + 256);
            const float4* h1g = reinterpret_cast<const float4*>(out + (size_t)src * 512 + 320);
            // h0 row: this slice's 8 floats
            float4 ga = h0g[2 * q], gb = h0g[2 * q + 1];
            *reinterpret_cast<float4*>(&h0_t[e0 * 68 + q * 8]) = ga;
            *reinterpret_cast<float4*>(&h0_t[e0 * 68 + q * 8 + 4]) = gb;
            // h1 row: this slice's 24 floats
#pragma unroll
            for (int k = 0; k < 6; k++) {
                float4 v = h1g[6 * q + k];
                *reinterpret_cast<float4*>(&h1_t[e0 * 196 + q * 24 + k * 4]) = v;
            }
            // hidden h[l] for l = q*8 .. q*8+7
            const float4* efp = reinterpret_cast<const float4*>(edge_feats + (size_t)eg * 8);
            float4 efa = efp[0], efb = efp[1];
            float hv0 = 0.f, hv1 = 0.f, hv2 = 0.f, hv3 = 0.f;
            float hv4 = 0.f, hv5 = 0.f, hv6 = 0.f, hv7 = 0.f;
            float4 wva, wvb;
#define H8(EFR, RR) \
            wva = *reinterpret_cast<const float4*>(&sW1[(RR) * 64 + q * 8]); \
            wvb = *reinterpret_cast<const float4*>(&sW1[(RR) * 64 + q * 8 + 4]); \
            hv0 += (EFR) * wva.x; hv1 += (EFR) * wva.y; hv2 += (EFR) * wva.z; hv3 += (EFR) * wva.w; \
            hv4 += (EFR) * wvb.x; hv5 += (EFR) * wvb.y; hv6 += (EFR) * wvb.z; hv7 += (EFR) * wvb.w;
            H8(efa.x, 0) H8(efa.y, 1) H8(efa.z, 2) H8(efa.w, 3)
            H8(efb.x, 4) H8(efb.y, 5) H8(efb.z, 6) H8(efb.w, 7)
#undef H8
            float4 o1 = make_float4(silu(hv0), silu(hv1), silu(hv2), silu(hv3));
            float4 o2 = make_float4(silu(hv4), silu(hv5), silu(hv6), silu(hv7));
            *reinterpret_cast<float4*>(&h_t[e0 * 68 + q * 8]) = o1;
            *reinterpret_cast<float4*>(&h_t[e0 * 68 + q * 8 + 4]) = o2;
        }
        __syncthreads();

        // ---- stage 1: w = h @ W2, register-blocked 4 edges x 8 channels ----
        {
            float4 accA0 = {0,0,0,0}, accA1 = {0,0,0,0}, accA2 = {0,0,0,0}, accA3 = {0,0,0,0};
            float4 accB0 = {0,0,0,0}, accB1 = {0,0,0,0}, accB2 = {0,0,0,0}, accB3 = {0,0,0,0};
            int eb = g * 4;
#pragma unroll 4
            for (int lq = 0; lq < 16; lq++) {
                float4 ha0 = h4[(eb + 0) * 17 + lq];
                float4 ha1 = h4[(eb + 1) * 17 + lq];
                float4 ha2 = h4[(eb + 2) * 17 + lq];
                float4 ha3 = h4[(eb + 3) * 17 + lq];
#define S1LI(LI, CMP) { \
                float4 wA = w24[(lq * 4 + LI) * 64 + cs]; \
                float4 wB = w24[(lq * 4 + LI) * 64 + 32 + cs]; \
                FMA4(accA0, ha0.CMP, wA) FMA4(accB0, ha0.CMP, wB) \
                FMA4(accA1, ha1.CMP, wA) FMA4(accB1, ha1.CMP, wB) \
                FMA4(accA2, ha2.CMP, wA) FMA4(accB2, ha2.CMP, wB) \
                FMA4(accA3, ha3.CMP, wA) FMA4(accB3, ha3.CMP, wB) }
                S1LI(0, x) S1LI(1, y) S1LI(2, z) S1LI(3, w)
#undef S1LI
            }
            wt4[(eb + 0) * 65 + cs] = accA0; wt4[(eb + 0) * 65 + 32 + cs] = accB0;
            wt4[(eb + 1) * 65 + cs] = accA1; wt4[(eb + 1) * 65 + 32 + cs] = accB1;
            wt4[(eb + 2) * 65 + cs] = accA2; wt4[(eb + 2) * 65 + 32 + cs] = accB2;
            wt4[(eb + 3) * 65 + cs] = accA3; wt4[(eb + 3) * 65 + 32 + cs] = accB3;
        }
        __syncthreads();

        // ---- stage 2: channel-parallel TP + register run-accumulate ----
        for (int e = 0; e < n_t; e++) {
            int d = dstl[e];
            float4 m = meta4[e];
            if (d != prev) {
                if (prev >= 0) atomicAdd(&accs[prev * 256 + off2], racc);
                racc = 0.f;
                prev = d;
            }
            float h0e = h0_t[e * 68 + c];
            if (wv == 0) {
                float w00 = w_t[e * 260 + c];
                float w11 = w_t[e * 260 + 64 + c];
                float x1 = h1_t[e * 196 + c * 3 + 0];
                float y1 = h1_t[e * 196 + c * 3 + 1];
                float z1 = h1_t[e * 196 + c * 3 + 2];
                float dd = x1 * m.x + y1 * m.y + z1 * m.z;
                racc += (w00 * h0e + w11 * dd) * m.w;
            } else {
                int i = wv - 1;
                float w01 = w_t[e * 260 + 128 + c];
                float w10 = w_t[e * 260 + 192 + c];
                float h1i = h1_t[e * 196 + c * 3 + i];
                float shi = (wv == 1) ? m.x : ((wv == 2) ? m.y : m.z);
                racc += (w01 * h0e * shi + w10 * h1i) * m.w;
            }
        }
        __syncthreads();   // protect tile buffers before next stage 0
    }
    if (prev >= 0) atomicAdd(&accs[prev * 256 + off2], racc);
    __syncthreads();

    // plain coalesced store of raw T0/T1 (finalize applies 1/16 and Q)
    for (int i = t; i < NB * 256; i += 256) {
        int ln = i >> 8, idx = i & 255;
        if (n0 + ln < Nn) out[(size_t)(n0 + ln) * 512 + idx] = accs[i];
    }
}

// ---------------- FALLBACK: original fused atomic-scatter edge kernel
__global__ __launch_bounds__(256, 2) void edge_kernel(
    const float* __restrict__ edge_feats, const float* __restrict__ edge_attrs1,
    const float* __restrict__ cutoff, const int* __restrict__ edge_index,
    const float* __restrict__ W1g, const float* __restrict__ W2g,
    float* __restrict__ out, int E) {
    __shared__ __align__(16) float sW1[8 * 64];
    __shared__ __align__(16) float sW2[64 * 256];
    int t = threadIdx.x;
    sW1[t] = W1g[t];
    sW1[t + 256] = W1g[t + 256];
    for (int i = t; i < 16384; i += 256) sW2[i] = W2g[i];
    __syncthreads();

    int e = blockIdx.x * 256 + t;
    if (e >= E) return;

    float ef[8];
    {
        const float4* p = reinterpret_cast<const float4*>(edge_feats + (size_t)e * 8);
        float4 a = p[0], b = p[1];
        ef[0] = a.x; ef[1] = a.y; ef[2] = a.z; ef[3] = a.w;
        ef[4] = b.x; ef[5] = b.y; ef[6] = b.z; ef[7] = b.w;
    }
    float h[64];
#pragma unroll
    for (int hg = 0; hg < 16; hg++) {
        float ax = 0.f, ay = 0.f, az = 0.f, aw = 0.f;
#pragma unroll
        for (int rr = 0; rr < 8; rr++) {
            const float4 wv = *reinterpret_cast<const float4*>(&sW1[rr * 64 + hg * 4]);
            ax += ef[rr] * wv.x; ay += ef[rr] * wv.y;
            az += ef[rr] * wv.z; aw += ef[rr] * wv.w;
        }
        h[hg * 4 + 0] = silu(ax);
        h[hg * 4 + 1] = silu(ay);
        h[hg * 4 + 2] = silu(az);
        h[hg * 4 + 3] = silu(aw);
    }

    int src = edge_index[e];
    int dst = edge_index[(size_t)E + e];
    float cut = cutoff[e];
    float sh0 = edge_attrs1[(size_t)e * 3 + 0];
    float sh1v = edge_attrs1[(size_t)e * 3 + 1];
    float sh2 = edge_attrs1[(size_t)e * 3 + 2];
    const float* h0r = out + (size_t)src * 512 + 256;
    const float* h1r = out + (size_t)src * 512 + 320;
    float* outr = out + (size_t)dst * 512;
    const float4* w2v = reinterpret_cast<const float4*>(sW2);

#pragma unroll 1
    for (int cg = 0; cg < 16; cg++) {
        float a00[4] = {0.f, 0.f, 0.f, 0.f};
        float a11[4] = {0.f, 0.f, 0.f, 0.f};
        float a01[4] = {0.f, 0.f, 0.f, 0.f};
        float a10[4] = {0.f, 0.f, 0.f, 0.f};
#pragma unroll
        for (int l = 0; l < 64; l++) {
            float hl = h[l];
            float4 w00v = w2v[l * 64 + cg];
            float4 w11v = w2v[l * 64 + 16 + cg];
            float4 w01v = w2v[l * 64 + 32 + cg];
            float4 w10v = w2v[l * 64 + 48 + cg];
            a00[0] += hl * w00v.x; a00[1] += hl * w00v.y; a00[2] += hl * w00v.z; a00[3] += hl * w00v.w;
            a11[0] += hl * w11v.x; a11[1] += hl * w11v.y; a11[2] += hl * w11v.z; a11[3] += hl * w11v.w;
            a01[0] += hl * w01v.x; a01[1] += hl * w01v.y; a01[2] += hl * w01v.z; a01[3] += hl * w01v.w;
            a10[0] += hl * w10v.x; a10[1] += hl * w10v.y; a10[2] += hl * w10v.z; a10[3] += hl * w10v.w;
        }
        int c0 = cg * 4;
        float4 h0v = *reinterpret_cast<const float4*>(h0r + c0);
        float4 q0 = *reinterpret_cast<const float4*>(h1r + c0 * 3);
        float4 q1 = *reinterpret_cast<const float4*>(h1r + c0 * 3 + 4);
        float4 q2 = *reinterpret_cast<const float4*>(h1r + c0 * 3 + 8);
        float h0a[4] = {h0v.x, h0v.y, h0v.z, h0v.w};
        float h1a[12] = {q0.x, q0.y, q0.z, q0.w, q1.x, q1.y, q1.z, q1.w,
                         q2.x, q2.y, q2.z, q2.w};
#pragma unroll
        for (int k = 0; k < 4; k++) {
            int c = c0 + k;
            float he0 = h0a[k];
            float e0 = h1a[k * 3 + 0], e1 = h1a[k * 3 + 1], e2 = h1a[k * 3 + 2];
            float d = e0 * sh0 + e1 * sh1v + e2 * sh2;
            float m0 = (a00[k] * he0 + a11[k] * d) * cut;
            atomicAdd(outr + c, m0);
            float wa = a01[k] * he0 * cut;
            float wb = a10[k] * cut;
            atomicAdd(outr + 64 + c * 3 + 0, wa * sh0 + wb * e0);
            atomicAdd(outr + 64 + c * 3 + 1, wa * sh1v + wb * e1);
            atomicAdd(outr + 64 + c * 3 + 2, wa * sh2 + wb * e2);
        }
    }
}

// ---------------- finalize: scale by 1/16, apply Q0/Q1, species residual
__global__ __launch_bounds__(256) void finalize_kernel(
    const float* __restrict__ node_attrs, const float* __restrict__ Wsc0,
    const float* __restrict__ Wsc1, const float* __restrict__ Q0,
    const float* __restrict__ Q1, float* __restrict__ out, int Nn) {
    __shared__ float smi0[4][64];
    __shared__ float smi1[4][192];
    int t = threadIdx.x;
    int w = t >> 6, o = t & 63;
    int n = blockIdx.x * 4 + w;
    const float inv = 1.0f / 16.0f;
    float q00 = Q0[0];
    float Q[9];
#pragma unroll
    for (int i = 0; i < 9; i++) Q[i] = Q1[i];
    if (n < Nn) {
        float* row = out + (size_t)n * 512;
        float t0 = row[o];
        float ta = row[64 + o * 3 + 0];
        float tb = row[64 + o * 3 + 1];
        float tc = row[64 + o * 3 + 2];
        float mi0 = t0 * inv * q00;
        float m0i = inv * (ta * Q[0] + tb * Q[3] + tc * Q[6]);
        float m1i = inv * (ta * Q[1] + tb * Q[4] + tc * Q[7]);
        float m2i = inv * (ta * Q[2] + tb * Q[5] + tc * Q[8]);
        row[o] = mi0;
        row[64 + o * 3 + 0] = m0i;
        row[64 + o * 3 + 1] = m1i;
        row[64 + o * 3 + 2] = m2i;
        smi0[w][o] = mi0;
        smi1[w][o * 3 + 0] = m0i;
        smi1[w][o * 3 + 1] = m1i;
        smi1[w][o * 3 + 2] = m2i;
    }
    __syncthreads();
    if (n >= Nn) return;
    float acc0 = 0.f, acc1x = 0.f, acc1y = 0.f, acc1z = 0.f;
    for (int s = 0; s < 10; s++) {
        float a = node_attrs[(size_t)n * 10 + s];
        if (a != 0.f) {
            const float* w0 = Wsc0 + s * 4096;
            const float* w1 = Wsc1 + s * 4096;
            float p0 = 0.f, px = 0.f, py = 0.f, pz = 0.f;
#pragma unroll 8
            for (int c = 0; c < 64; c++) {
                float v0 = w0[c * 64 + o];
                float v1 = w1[c * 64 + o];
                p0 += smi0[w][c] * v0;
                px += smi1[w][c * 3 + 0] * v1;
                py += smi1[w][c * 3 + 1] * v1;
                pz += smi1[w][c * 3 + 2] * v1;
            }
            acc0 += a * p0; acc1x += a * px; acc1y += a * py; acc1z += a * pz;
        }
    }
    float* row = out + (size_t)n * 512;
    row[256 + o] = acc0;
    row[320 + o * 3 + 0] = acc1x;
    row[320 + o * 3 + 1] = acc1y;
    row[320 + o * 3 + 2] = acc1z;
}

extern "C" void kernel_launch(void* const* d_in, const int* in_sizes, int n_in,
                              void* d_out, int out_size, void* d_ws, size_t ws_size,
                              hipStream_t stream) {
    const float* nf0   = (const float*)d_in[0];
    const float* nf1   = (const float*)d_in[1];
    const float* attrs = (const float*)d_in[2];
    const float* ef    = (const float*)d_in[3];
    const float* ea1   = (const float*)d_in[4];
    const float* cut   = (const float*)d_in[5];
    const float* Wup0  = (const float*)d_in[6];
    const float* Wup1  = (const float*)d_in[7];
    const float* W1    = (const float*)d_in[8];
    const float* W2    = (const float*)d_in[9];
    const float* Wsc0  = (const float*)d_in[10];
    const float* Wsc1  = (const float*)d_in[11];
    const float* Q0    = (const float*)d_in[12];
    const float* Q1    = (const float*)d_in[13];
    const int*   ei    = (const int*)d_in[14];
    int Nn = in_sizes[0] / 64;      // 50000
    int E  = in_sizes[14] / 2;      // 800000
    float* out = (float*)d_out;

    // ws layout (ints): cnt/offs [Nn+1] | cur [Nn] | csr [E]
    size_t need_bytes = ((size_t)(2 * Nn + 1) + (size_t)E) * sizeof(int);
    int ebl = (E + 255) / 256;

    if (d_ws != nullptr && ws_size >= need_bytes) {
        int* cnt = (int*)d_ws;
        int* cur = cnt + (Nn + 1);
        int* csr = cur + Nn;
        hipMemsetAsync(cnt, 0, (size_t)(Nn + 1) * sizeof(int), stream);
        hist_kernel<<<ebl, 256, 0, stream>>>(ei, cnt, E);
        scan_kernel<<<1, 1024, 0, stream>>>(cnt, cur, Nn, E);
        fill_kernel<<<ebl, 256, 0, stream>>>(ei, cur, csr, E);
        up_kernel<<<(Nn + 3) / 4, 256, 0, stream>>>(nf0, nf1, Wup0, Wup1, out, Nn);
        gather_kernel<<<(Nn + NB - 1) / NB, 256, 0, stream>>>(
            ef, ea1, cut, ei, cnt, csr, W1, W2, out, Nn, E);
        finalize_kernel<<<(Nn + 3) / 4, 256, 0, stream>>>(attrs, Wsc0, Wsc1, Q0, Q1, out, Nn);
    } else {
        // fallback: original atomic-scatter path (out must be zeroed)
        hipMemsetAsync(out, 0, (size_t)out_size * sizeof(float), stream);
        up_kernel<<<(Nn + 3) / 4, 256, 0, stream>>>(nf0, nf1, Wup0, Wup1, out, Nn);
        edge_kernel<<<ebl, 256, 0, stream>>>(ef, ea1, cut, ei, W1, W2, out, E);
        finalize_kernel<<<(Nn + 3) / 4, 256, 0, stream>>>(attrs, Wsc0, Wsc1, Q0, Q1, out, Nn);
    }
}

// Round 5
// 1605.036 us; speedup vs baseline: 1.9448x; 1.1373x over previous
//
#include <hip/hip_runtime.h>
#include <math.h>

// N=50000 nodes, E=800000 edges, C=64, R=8, H=64, S=10
// Output row layout (512 floats/node): [mi0:64 | mi1:192 | res0:64 | res1:192]
// h0/h1 (linear_up output) live temporarily in cols 256:512 of d_out.
//
// FAST PATH: CSR (dst-sorted edge ids) built per call, then a node-owned
// 3-stage tile-pipelined gather kernel (256 thr, NB=16 nodes, 32-edge tiles):
//   prefetch: next tile's global gathers held in REGISTERS (T14 split) --
//             issued before stage1, committed to LDS at next tile top, so
//             HBM latency hides under ~18k cycles of compute (R4's 20k-cyc
//             per-tile stall was exposed gather latency at 1 block/CU).
//   stage0(commit): regs -> LDS tiles + radial-MLP hidden
//   stage1: register-blocked GEMM w = h @ W2 (4 edges x 8 ch per thread)
//   stage2: wave wv owns edges e%4==wv; each thread = 1 channel x ALL 4
//           components in registers; ds_add only at dst-change.

#define NB 16        // nodes per gather block
#define TE 32        // edges per tile

__device__ __forceinline__ float silu(float x) {
    return x / (1.0f + __expf(-x));
}

// ---------------- linear_up: h0 = nf0@Wup0, h1[n,o,i] = sum_c nf1[n,c,i]*Wup1[c,o]
__global__ __launch_bounds__(256) void up_kernel(
    const float* __restrict__ nf0, const float* __restrict__ nf1,
    const float* __restrict__ Wup0, const float* __restrict__ Wup1,
    float* __restrict__ out, int Nn) {
    __shared__ float sW0[4096];
    __shared__ float sW1u[4096];
    __shared__ float s0[4 * 64];
    __shared__ float s1[4 * 192];
    int t = threadIdx.x;
    for (int i = t; i < 4096; i += 256) { sW0[i] = Wup0[i]; sW1u[i] = Wup1[i]; }
    int n0 = blockIdx.x * 4;
    {
        int n = n0 + (t >> 6);
        s0[t] = (n < Nn) ? nf0[(size_t)n * 64 + (t & 63)] : 0.f;
    }
    for (int i = t; i < 768; i += 256) {
        int n = n0 + i / 192;
        s1[i] = (n < Nn) ? nf1[(size_t)n * 192 + (i % 192)] : 0.f;
    }
    __syncthreads();
    int w = t >> 6, o = t & 63;
    int n = n0 + w;
    if (n >= Nn) return;
    float a0 = 0.f, ax = 0.f, ay = 0.f, az = 0.f;
#pragma unroll 8
    for (int c = 0; c < 64; c++) {
        float w0 = sW0[c * 64 + o];
        float w1 = sW1u[c * 64 + o];
        float f0 = s0[w * 64 + c];
        a0 += f0 * w0;
        ax += s1[w * 192 + c * 3 + 0] * w1;
        ay += s1[w * 192 + c * 3 + 1] * w1;
        az += s1[w * 192 + c * 3 + 2] * w1;
    }
    float* row = out + (size_t)n * 512;
    row[256 + o] = a0;
    row[320 + o * 3 + 0] = ax;
    row[320 + o * 3 + 1] = ay;
    row[320 + o * 3 + 2] = az;
}

// ---------------- CSR build: histogram, exclusive scan, fill
__global__ __launch_bounds__(256) void hist_kernel(
    const int* __restrict__ ei, int* __restrict__ cnt, int E) {
    int e = blockIdx.x * 256 + threadIdx.x;
    if (e < E) atomicAdd(&cnt[ei[(size_t)E + e]], 1);
}

__global__ __launch_bounds__(1024) void scan_kernel(
    int* __restrict__ cnt, int* __restrict__ cur, int Nn, int E) {
    __shared__ int wsum[16];
    __shared__ int carry_s;
    int t = threadIdx.x;
    int lane = t & 63, wid = t >> 6;
    if (t == 0) carry_s = 0;
    __syncthreads();
    int nchunk = (Nn + 1023) >> 10;
    for (int ch = 0; ch < nchunk; ch++) {
        int i = (ch << 10) + t;
        int v = (i < Nn) ? cnt[i] : 0;
        int s = v;
#pragma unroll
        for (int d = 1; d < 64; d <<= 1) {
            int u = __shfl_up(s, d);
            if (lane >= d) s += u;
        }
        if (lane == 63) wsum[wid] = s;
        __syncthreads();
        int carry = carry_s;
        if (wid == 0) {
            int x = (lane < 16) ? wsum[lane] : 0;
#pragma unroll
            for (int d = 1; d < 16; d <<= 1) {
                int u = __shfl_up(x, d);
                if (lane >= d) x += u;
            }
            if (lane < 16) wsum[lane] = x;
        }
        __syncthreads();
        int woff = wid ? wsum[wid - 1] : 0;
        int excl = carry + woff + (s - v);
        if (i < Nn) { cnt[i] = excl; cur[i] = excl; }
        __syncthreads();
        if (t == 1023) carry_s = carry + wsum[15];
        __syncthreads();
    }
    if (t == 0) cnt[Nn] = E;
}

__global__ __launch_bounds__(256) void fill_kernel(
    const int* __restrict__ ei, int* __restrict__ cur, int* __restrict__ csr, int E) {
    int e = blockIdx.x * 256 + threadIdx.x;
    if (e < E) {
        int pos = atomicAdd(&cur[ei[(size_t)E + e]], 1);
        csr[pos] = e;
    }
}

#define FMA4(A, S, B) { (A).x += (S)*(B).x; (A).y += (S)*(B).y; (A).z += (S)*(B).z; (A).w += (S)*(B).w; }

// ---------------- 3-stage tile-pipelined node-owned gather w/ register prefetch
__global__ __launch_bounds__(256, 1) void gather_kernel(
    const float* __restrict__ edge_feats, const float* __restrict__ edge_attrs1,
    const float* __restrict__ cutoff, const int* __restrict__ ei,
    const int* __restrict__ offs, const int* __restrict__ csr,
    const float* __restrict__ W1g, const float* __restrict__ W2g,
    float* __restrict__ out, int Nn, int E) {
    __shared__ __align__(16) float sW1[512];          //  2048 B
    __shared__ __align__(16) float sW2[64 * 256];     // 65536 B
    __shared__ __align__(16) float h_t[TE * 68];      //  8704 B (hidden, pad 68)
    __shared__ __align__(16) float h0_t[TE * 68];     //  8704 B
    __shared__ __align__(16) float h1_t[TE * 196];    // 25088 B (pad 196)
    __shared__ __align__(16) float w_t[TE * 260];     // 33280 B (pad 260)
    __shared__ __align__(16) float accs[NB * 256];    // 16384 B
    __shared__ __align__(16) float4 meta4[TE];        //   512 B (sh0,sh1,sh2,cut)
    __shared__ int dstl[TE];                          //   128 B  => 160384 B total
    int t = threadIdx.x;

    for (int i = t; i < 512; i += 256) sW1[i] = W1g[i];
    {
        float4* d4 = reinterpret_cast<float4*>(sW2);
        const float4* s4 = reinterpret_cast<const float4*>(W2g);
        for (int i = t; i < 4096; i += 256) d4[i] = s4[i];
    }
    for (int i = t; i < NB * 256; i += 256) accs[i] = 0.f;
    int n0 = blockIdx.x * NB;
    int nend = n0 + NB; if (nend > Nn) nend = Nn;
    int pbeg = offs[n0];
    int pend = offs[nend];
    __syncthreads();

    // stage role indices
    int e0 = t >> 3, q = t & 7;          // stage 0: 32 edges x 8 slices
    int g = t >> 5, cs = t & 31;         // stage 1: 8 groups(4e) x 32 ch-slices
    int wv = t >> 6, c = t & 63;         // stage 2: wave = edge-subset e%4==wv

    const float4* h4  = reinterpret_cast<const float4*>(h_t);   // row stride 17
    const float4* w24 = reinterpret_cast<const float4*>(sW2);   // row stride 64
    float4* wt4 = reinterpret_cast<float4*>(w_t);               // row stride 65

    // stage-2 run accumulators (persist across tiles)
    float r0 = 0.f, rx = 0.f, ry = 0.f, rz = 0.f;
    int prev = -1;

    // prefetch registers (tile t+1 gather data, committed at next tile top)
    float4 pf_h0a, pf_h0b, pf_ef0, pf_ef1;
    float4 pf_h10, pf_h11, pf_h12, pf_h13, pf_h14, pf_h15;
    float4 pf_meta;
    int pf_dst = 0;
    bool pf_valid = false;

    auto prefetch = [&](int tbn) {
        int nt2 = pend - tbn; if (nt2 > TE) nt2 = TE;
        pf_valid = (e0 < nt2);
        if (pf_valid) {
            int eg = csr[tbn + e0];
            int src = ei[eg];
            if (q == 0) {
                pf_dst = ei[(size_t)E + eg] - n0;
                pf_meta = make_float4(edge_attrs1[(size_t)eg * 3 + 0],
                                      edge_attrs1[(size_t)eg * 3 + 1],
                                      edge_attrs1[(size_t)eg * 3 + 2],
                                      cutoff[eg]);
            }
            const float4* h0g = reinterpret_cast<const float4*>(out + (size_t)src * 512 + 256);
            const float4* h1g = reinterpret_cast<const float4*>(out + (size_t)src * 512 + 320);
            pf_h0a = h0g[2 * q]; pf_h0b = h0g[2 * q + 1];
            pf_h10 = h1g[6 * q + 0]; pf_h11 = h1g[6 * q + 1]; pf_h12 = h1g[6 * q + 2];
            pf_h13 = h1g[6 * q + 3]; pf_h14 = h1g[6 * q + 4]; pf_h15 = h1g[6 * q + 5];
            const float4* efp = reinterpret_cast<const float4*>(edge_feats + (size_t)eg * 8);
            pf_ef0 = efp[0]; pf_ef1 = efp[1];
        }
    };

    prefetch(pbeg);   // prologue (not hidden; every later one is)

    for (int tb = pbeg; tb < pend; tb += TE) {
        int n_t = pend - tb; if (n_t > TE) n_t = TE;

        // ---- stage 0 (commit): regs -> LDS tiles + radial MLP hidden ----
        if (pf_valid) {
            if (q == 0) { dstl[e0] = pf_dst; meta4[e0] = pf_meta; }
            *reinterpret_cast<float4*>(&h0_t[e0 * 68 + q * 8]) = pf_h0a;
            *reinterpret_cast<float4*>(&h0_t[e0 * 68 + q * 8 + 4]) = pf_h0b;
            *reinterpret_cast<float4*>(&h1_t[e0 * 196 + q * 24 + 0])  = pf_h10;
            *reinterpret_cast<float4*>(&h1_t[e0 * 196 + q * 24 + 4])  = pf_h11;
            *reinterpret_cast<float4*>(&h1_t[e0 * 196 + q * 24 + 8])  = pf_h12;
            *reinterpret_cast<float4*>(&h1_t[e0 * 196 + q * 24 + 12]) = pf_h13;
            *reinterpret_cast<float4*>(&h1_t[e0 * 196 + q * 24 + 16]) = pf_h14;
            *reinterpret_cast<float4*>(&h1_t[e0 * 196 + q * 24 + 20]) = pf_h15;
            // hidden h[l] for l = q*8 .. q*8+7
            float hv0 = 0.f, hv1 = 0.f, hv2 = 0.f, hv3 = 0.f;
            float hv4 = 0.f, hv5 = 0.f, hv6 = 0.f, hv7 = 0.f;
            float4 wva, wvb;
#define H8(EFR, RR) \
            wva = *reinterpret_cast<const float4*>(&sW1[(RR) * 64 + q * 8]); \
            wvb = *reinterpret_cast<const float4*>(&sW1[(RR) * 64 + q * 8 + 4]); \
            hv0 += (EFR) * wva.x; hv1 += (EFR) * wva.y; hv2 += (EFR) * wva.z; hv3 += (EFR) * wva.w; \
            hv4 += (EFR) * wvb.x; hv5 += (EFR) * wvb.y; hv6 += (EFR) * wvb.z; hv7 += (EFR) * wvb.w;
            H8(pf_ef0.x, 0) H8(pf_ef0.y, 1) H8(pf_ef0.z, 2) H8(pf_ef0.w, 3)
            H8(pf_ef1.x, 4) H8(pf_ef1.y, 5) H8(pf_ef1.z, 6) H8(pf_ef1.w, 7)
#undef H8
            float4 o1 = make_float4(silu(hv0), silu(hv1), silu(hv2), silu(hv3));
            float4 o2 = make_float4(silu(hv4), silu(hv5), silu(hv6), silu(hv7));
            *reinterpret_cast<float4*>(&h_t[e0 * 68 + q * 8]) = o1;
            *reinterpret_cast<float4*>(&h_t[e0 * 68 + q * 8 + 4]) = o2;
        }
        __syncthreads();

        // ---- issue next tile's global loads (hidden under stage1+stage2) ----
        if (tb + TE < pend) prefetch(tb + TE); else pf_valid = false;

        // ---- stage 1: w = h @ W2, register-blocked 4 edges x 8 channels ----
        {
            float4 accA0 = {0,0,0,0}, accA1 = {0,0,0,0}, accA2 = {0,0,0,0}, accA3 = {0,0,0,0};
            float4 accB0 = {0,0,0,0}, accB1 = {0,0,0,0}, accB2 = {0,0,0,0}, accB3 = {0,0,0,0};
            int eb = g * 4;
#pragma unroll 4
            for (int lq = 0; lq < 16; lq++) {
                float4 ha0 = h4[(eb + 0) * 17 + lq];
                float4 ha1 = h4[(eb + 1) * 17 + lq];
                float4 ha2 = h4[(eb + 2) * 17 + lq];
                float4 ha3 = h4[(eb + 3) * 17 + lq];
#define S1LI(LI, CMP) { \
                float4 wA = w24[(lq * 4 + LI) * 64 + cs]; \
                float4 wB = w24[(lq * 4 + LI) * 64 + 32 + cs]; \
                FMA4(accA0, ha0.CMP, wA) FMA4(accB0, ha0.CMP, wB) \
                FMA4(accA1, ha1.CMP, wA) FMA4(accB1, ha1.CMP, wB) \
                FMA4(accA2, ha2.CMP, wA) FMA4(accB2, ha2.CMP, wB) \
                FMA4(accA3, ha3.CMP, wA) FMA4(accB3, ha3.CMP, wB) }
                S1LI(0, x) S1LI(1, y) S1LI(2, z) S1LI(3, w)
#undef S1LI
            }
            wt4[(eb + 0) * 65 + cs] = accA0; wt4[(eb + 0) * 65 + 32 + cs] = accB0;
            wt4[(eb + 1) * 65 + cs] = accA1; wt4[(eb + 1) * 65 + 32 + cs] = accB1;
            wt4[(eb + 2) * 65 + cs] = accA2; wt4[(eb + 2) * 65 + 32 + cs] = accB2;
            wt4[(eb + 3) * 65 + cs] = accA3; wt4[(eb + 3) * 65 + 32 + cs] = accB3;
        }
        __syncthreads();

        // ---- stage 2: wave wv takes edges e%4==wv; all 4 comps per thread ----
        for (int e = wv; e < n_t; e += 4) {
            int d = dstl[e];
            float4 m = meta4[e];
            if (d != prev) {
                if (prev >= 0) {
                    atomicAdd(&accs[prev * 256 + c], r0);
                    atomicAdd(&accs[prev * 256 + 64 + c * 3 + 0], rx);
                    atomicAdd(&accs[prev * 256 + 64 + c * 3 + 1], ry);
                    atomicAdd(&accs[prev * 256 + 64 + c * 3 + 2], rz);
                }
                r0 = rx = ry = rz = 0.f;
                prev = d;
            }
            float h0e = h0_t[e * 68 + c];
            float w00 = w_t[e * 260 + c];
            float w11 = w_t[e * 260 + 64 + c];
            float w01 = w_t[e * 260 + 128 + c];
            float w10 = w_t[e * 260 + 192 + c];
            float x1 = h1_t[e * 196 + c * 3 + 0];
            float y1 = h1_t[e * 196 + c * 3 + 1];
            float z1 = h1_t[e * 196 + c * 3 + 2];
            float dd = x1 * m.x + y1 * m.y + z1 * m.z;
            r0 += (w00 * h0e + w11 * dd) * m.w;
            float wa = w01 * h0e * m.w;
            float wb = w10 * m.w;
            rx += wa * m.x + wb * x1;
            ry += wa * m.y + wb * y1;
            rz += wa * m.z + wb * z1;
        }
        __syncthreads();   // protect tile buffers before next commit
    }
    if (prev >= 0) {
        atomicAdd(&accs[prev * 256 + c], r0);
        atomicAdd(&accs[prev * 256 + 64 + c * 3 + 0], rx);
        atomicAdd(&accs[prev * 256 + 64 + c * 3 + 1], ry);
        atomicAdd(&accs[prev * 256 + 64 + c * 3 + 2], rz);
    }
    __syncthreads();

    // plain coalesced store of raw T0/T1 (finalize applies 1/16 and Q)
    for (int i = t; i < NB * 256; i += 256) {
        int ln = i >> 8, idx = i & 255;
        if (n0 + ln < Nn) out[(size_t)(n0 + ln) * 512 + idx] = accs[i];
    }
}

// ---------------- FALLBACK: original fused atomic-scatter edge kernel
__global__ __launch_bounds__(256, 2) void edge_kernel(
    const float* __restrict__ edge_feats, const float* __restrict__ edge_attrs1,
    const float* __restrict__ cutoff, const int* __restrict__ edge_index,
    const float* __restrict__ W1g, const float* __restrict__ W2g,
    float* __restrict__ out, int E) {
    __shared__ __align__(16) float sW1[8 * 64];
    __shared__ __align__(16) float sW2[64 * 256];
    int t = threadIdx.x;
    sW1[t] = W1g[t];
    sW1[t + 256] = W1g[t + 256];
    for (int i = t; i < 16384; i += 256) sW2[i] = W2g[i];
    __syncthreads();

    int e = blockIdx.x * 256 + t;
    if (e >= E) return;

    float ef[8];
    {
        const float4* p = reinterpret_cast<const float4*>(edge_feats + (size_t)e * 8);
        float4 a = p[0], b = p[1];
        ef[0] = a.x; ef[1] = a.y; ef[2] = a.z; ef[3] = a.w;
        ef[4] = b.x; ef[5] = b.y; ef[6] = b.z; ef[7] = b.w;
    }
    float h[64];
#pragma unroll
    for (int hg = 0; hg < 16; hg++) {
        float ax = 0.f, ay = 0.f, az = 0.f, aw = 0.f;
#pragma unroll
        for (int rr = 0; rr < 8; rr++) {
            const float4 wv = *reinterpret_cast<const float4*>(&sW1[rr * 64 + hg * 4]);
            ax += ef[rr] * wv.x; ay += ef[rr] * wv.y;
            az += ef[rr] * wv.z; aw += ef[rr] * wv.w;
        }
        h[hg * 4 + 0] = silu(ax);
        h[hg * 4 + 1] = silu(ay);
        h[hg * 4 + 2] = silu(az);
        h[hg * 4 + 3] = silu(aw);
    }

    int src = edge_index[e];
    int dst = edge_index[(size_t)E + e];
    float cut = cutoff[e];
    float sh0 = edge_attrs1[(size_t)e * 3 + 0];
    float sh1v = edge_attrs1[(size_t)e * 3 + 1];
    float sh2 = edge_attrs1[(size_t)e * 3 + 2];
    const float* h0r = out + (size_t)src * 512 + 256;
    const float* h1r = out + (size_t)src * 512 + 320;
    float* outr = out + (size_t)dst * 512;
    const float4* w2v = reinterpret_cast<const float4*>(sW2);

#pragma unroll 1
    for (int cg = 0; cg < 16; cg++) {
        float a00[4] = {0.f, 0.f, 0.f, 0.f};
        float a11[4] = {0.f, 0.f, 0.f, 0.f};
        float a01[4] = {0.f, 0.f, 0.f, 0.f};
        float a10[4] = {0.f, 0.f, 0.f, 0.f};
#pragma unroll
        for (int l = 0; l < 64; l++) {
            float hl = h[l];
            float4 w00v = w2v[l * 64 + cg];
            float4 w11v = w2v[l * 64 + 16 + cg];
            float4 w01v = w2v[l * 64 + 32 + cg];
            float4 w10v = w2v[l * 64 + 48 + cg];
            a00[0] += hl * w00v.x; a00[1] += hl * w00v.y; a00[2] += hl * w00v.z; a00[3] += hl * w00v.w;
            a11[0] += hl * w11v.x; a11[1] += hl * w11v.y; a11[2] += hl * w11v.z; a11[3] += hl * w11v.w;
            a01[0] += hl * w01v.x; a01[1] += hl * w01v.y; a01[2] += hl * w01v.z; a01[3] += hl * w01v.w;
            a10[0] += hl * w10v.x; a10[1] += hl * w10v.y; a10[2] += hl * w10v.z; a10[3] += hl * w10v.w;
        }
        int c0 = cg * 4;
        float4 h0v = *reinterpret_cast<const float4*>(h0r + c0);
        float4 q0 = *reinterpret_cast<const float4*>(h1r + c0 * 3);
        float4 q1 = *reinterpret_cast<const float4*>(h1r + c0 * 3 + 4);
        float4 q2 = *reinterpret_cast<const float4*>(h1r + c0 * 3 + 8);
        float h0a[4] = {h0v.x, h0v.y, h0v.z, h0v.w};
        float h1a[12] = {q0.x, q0.y, q0.z, q0.w, q1.x, q1.y, q1.z, q1.w,
                         q2.x, q2.y, q2.z, q2.w};
#pragma unroll
        for (int k = 0; k < 4; k++) {
            int c = c0 + k;
            float he0 = h0a[k];
            float e0 = h1a[k * 3 + 0], e1 = h1a[k * 3 + 1], e2 = h1a[k * 3 + 2];
            float d = e0 * sh0 + e1 * sh1v + e2 * sh2;
            float m0 = (a00[k] * he0 + a11[k] * d) * cut;
            atomicAdd(outr + c, m0);
            float wa = a01[k] * he0 * cut;
            float wb = a10[k] * cut;
            atomicAdd(outr + 64 + c * 3 + 0, wa * sh0 + wb * e0);
            atomicAdd(outr + 64 + c * 3 + 1, wa * sh1v + wb * e1);
            atomicAdd(outr + 64 + c * 3 + 2, wa * sh2 + wb * e2);
        }
    }
}

// ---------------- finalize: scale by 1/16, apply Q0/Q1, species residual
__global__ __launch_bounds__(256) void finalize_kernel(
    const float* __restrict__ node_attrs, const float* __restrict__ Wsc0,
    const float* __restrict__ Wsc1, const float* __restrict__ Q0,
    const float* __restrict__ Q1, float* __restrict__ out, int Nn) {
    __shared__ float smi0[4][64];
    __shared__ float smi1[4][192];
    int t = threadIdx.x;
    int w = t >> 6, o = t & 63;
    int n = blockIdx.x * 4 + w;
    const float inv = 1.0f / 16.0f;
    float q00 = Q0[0];
    float Q[9];
#pragma unroll
    for (int i = 0; i < 9; i++) Q[i] = Q1[i];
    if (n < Nn) {
        float* row = out + (size_t)n * 512;
        float t0 = row[o];
        float ta = row[64 + o * 3 + 0];
        float tb = row[64 + o * 3 + 1];
        float tc = row[64 + o * 3 + 2];
        float mi0 = t0 * inv * q00;
        float m0i = inv * (ta * Q[0] + tb * Q[3] + tc * Q[6]);
        float m1i = inv * (ta * Q[1] + tb * Q[4] + tc * Q[7]);
        float m2i = inv * (ta * Q[2] + tb * Q[5] + tc * Q[8]);
        row[o] = mi0;
        row[64 + o * 3 + 0] = m0i;
        row[64 + o * 3 + 1] = m1i;
        row[64 + o * 3 + 2] = m2i;
        smi0[w][o] = mi0;
        smi1[w][o * 3 + 0] = m0i;
        smi1[w][o * 3 + 1] = m1i;
        smi1[w][o * 3 + 2] = m2i;
    }
    __syncthreads();
    if (n >= Nn) return;
    float acc0 = 0.f, acc1x = 0.f, acc1y = 0.f, acc1z = 0.f;
    for (int s = 0; s < 10; s++) {
        float a = node_attrs[(size_t)n * 10 + s];
        if (a != 0.f) {
            const float* w0 = Wsc0 + s * 4096;
            const float* w1 = Wsc1 + s * 4096;
            float p0 = 0.f, px = 0.f, py = 0.f, pz = 0.f;
#pragma unroll 8
            for (int c = 0; c < 64; c++) {
                float v0 = w0[c * 64 + o];
                float v1 = w1[c * 64 + o];
                p0 += smi0[w][c] * v0;
                px += smi1[w][c * 3 + 0] * v1;
                py += smi1[w][c * 3 + 1] * v1;
                pz += smi1[w][c * 3 + 2] * v1;
            }
            acc0 += a * p0; acc1x += a * px; acc1y += a * py; acc1z += a * pz;
        }
    }
    float* row = out + (size_t)n * 512;
    row[256 + o] = acc0;
    row[320 + o * 3 + 0] = acc1x;
    row[320 + o * 3 + 1] = acc1y;
    row[320 + o * 3 + 2] = acc1z;
}

extern "C" void kernel_launch(void* const* d_in, const int* in_sizes, int n_in,
                              void* d_out, int out_size, void* d_ws, size_t ws_size,
                              hipStream_t stream) {
    const float* nf0   = (const float*)d_in[0];
    const float* nf1   = (const float*)d_in[1];
    const float* attrs = (const float*)d_in[2];
    const float* ef    = (const float*)d_in[3];
    const float* ea1   = (const float*)d_in[4];
    const float* cut   = (const float*)d_in[5];
    const float* Wup0  = (const float*)d_in[6];
    const float* Wup1  = (const float*)d_in[7];
    const float* W1    = (const float*)d_in[8];
    const float* W2    = (const float*)d_in[9];
    const float* Wsc0  = (const float*)d_in[10];
    const float* Wsc1  = (const float*)d_in[11];
    const float* Q0    = (const float*)d_in[12];
    const float* Q1    = (const float*)d_in[13];
    const int*   ei    = (const int*)d_in[14];
    int Nn = in_sizes[0] / 64;      // 50000
    int E  = in_sizes[14] / 2;      // 800000
    float* out = (float*)d_out;

    // ws layout (ints): cnt/offs [Nn+1] | cur [Nn] | csr [E]
    size_t need_bytes = ((size_t)(2 * Nn + 1) + (size_t)E) * sizeof(int);
    int ebl = (E + 255) / 256;

    if (d_ws != nullptr && ws_size >= need_bytes) {
        int* cnt = (int*)d_ws;
        int* cur = cnt + (Nn + 1);
        int* csr = cur + Nn;
        hipMemsetAsync(cnt, 0, (size_t)(Nn + 1) * sizeof(int), stream);
        hist_kernel<<<ebl, 256, 0, stream>>>(ei, cnt, E);
        scan_kernel<<<1, 1024, 0, stream>>>(cnt, cur, Nn, E);
        fill_kernel<<<ebl, 256, 0, stream>>>(ei, cur, csr, E);
        up_kernel<<<(Nn + 3) / 4, 256, 0, stream>>>(nf0, nf1, Wup0, Wup1, out, Nn);
        gather_kernel<<<(Nn + NB - 1) / NB, 256, 0, stream>>>(
            ef, ea1, cut, ei, cnt, csr, W1, W2, out, Nn, E);
        finalize_kernel<<<(Nn + 3) / 4, 256, 0, stream>>>(attrs, Wsc0, Wsc1, Q0, Q1, out, Nn);
    } else {
        // fallback: original atomic-scatter path (out must be zeroed)
        hipMemsetAsync(out, 0, (size_t)out_size * sizeof(float), stream);
        up_kernel<<<(Nn + 3) / 4, 256, 0, stream>>>(nf0, nf1, Wup0, Wup1, out, Nn);
        edge_kernel<<<ebl, 256, 0, stream>>>(ef, ea1, cut, ei, W1, W2, out, E);
        finalize_kernel<<<(Nn + 3) / 4, 256, 0, stream>>>(attrs, Wsc0, Wsc1, Q0, Q1, out, Nn);
    }
}